// Round 1
// baseline (178.803 us; speedup 1.0000x reference)
//
#include <hip/hip_runtime.h>
#include <hip/hip_bf16.h>

typedef unsigned short u16;
typedef __bf16 bf16x8 __attribute__((ext_vector_type(8)));
typedef float f32x4 __attribute__((ext_vector_type(4)));

#define GLDS16(g, l)                                                           \
  __builtin_amdgcn_global_load_lds(                                            \
      (const __attribute__((address_space(1))) unsigned int*)(g),              \
      (__attribute__((address_space(3))) unsigned int*)(l), 16, 0, 0)

static __device__ __forceinline__ u16 f2bf(float f) {
  unsigned int u = __builtin_bit_cast(unsigned int, f);
  u = (u + 0x7fffu + ((u >> 16) & 1u)) >> 16;
  return (u16)u;
}

// ---------------------------------------------------------------------------
// Kernel 1: W [768][1024] fp32 -> Wt [1024][768] bf16 (transpose via LDS tile)
// ---------------------------------------------------------------------------
__global__ __launch_bounds__(256) void wcast_kernel(const float* __restrict__ W,
                                                    u16* __restrict__ Wt) {
  __shared__ float tile[32][33];  // +1 pad breaks transpose bank conflicts
  const int n0 = blockIdx.x * 32;  // 0..1023
  const int k0 = blockIdx.y * 32;  // 0..767
  const int t = threadIdx.x;
#pragma unroll
  for (int i = 0; i < 4; i++) {
    int idx = t + i * 256;
    int r = idx >> 5, c = idx & 31;           // r = k-local, c = n-local
    tile[r][c] = W[(size_t)(k0 + r) * 1024 + n0 + c];
  }
  __syncthreads();
#pragma unroll
  for (int i = 0; i < 4; i++) {
    int idx = t + i * 256;
    int r = idx >> 5, c = idx & 31;           // r = n-local, c = k-local
    Wt[(size_t)(n0 + r) * 768 + k0 + c] = f2bf(tile[c][r]);
  }
}

// ---------------------------------------------------------------------------
// Kernel 2: masked sum over P -> X bf16 [4096][768]
// pv: [4096][8][768] fp32, np: [4096]
// ---------------------------------------------------------------------------
__global__ __launch_bounds__(192) void reduce_kernel(const float* __restrict__ pv,
                                                     const int* __restrict__ np,
                                                     u16* __restrict__ X) {
  const int pos = blockIdx.x;  // 4096
  const int t = threadIdx.x;   // 192, each thread does 4 floats (float4)
  const int c = np[pos];
  const float4* base = (const float4*)(pv + (size_t)pos * 8 * 768);
  float4 acc = make_float4(0.f, 0.f, 0.f, 0.f);
  for (int p = 0; p < c; p++) {
    float4 v = base[p * 192 + t];
    acc.x += v.x; acc.y += v.y; acc.z += v.z; acc.w += v.w;
  }
  ushort4 o;
  o.x = f2bf(acc.x); o.y = f2bf(acc.y); o.z = f2bf(acc.z); o.w = f2bf(acc.w);
  ((ushort4*)(X + (size_t)pos * 768))[t] = o;
}

// ---------------------------------------------------------------------------
// Kernel 3: Y[4096][1024] fp32 = X[4096][768]_bf16 @ Wt[1024][768]_bf16^T
// BM=128, BN=64, BK=32; 256 threads = 4 waves in 2x2, wave tile 64x32.
// global_load_lds width-16 staging (m97 structure).
// ---------------------------------------------------------------------------
__global__ __launch_bounds__(256) void gemm_kernel(const u16* __restrict__ A,
                                                   const u16* __restrict__ Bt,
                                                   float* __restrict__ Y) {
  __shared__ __attribute__((aligned(16))) u16 As[128 * 32];  // [m][k]
  __shared__ __attribute__((aligned(16))) u16 Bs[64 * 32];   // [n][k]
  const int tid = threadIdx.x;
  const int wave = tid >> 6;
  const int lane = tid & 63;
  const int m0 = blockIdx.y * 128;
  const int n0 = blockIdx.x * 64;

  // Staging: each 16B chunk = one (row, k-octet). Chunk c of a tile covers
  // rows [c*16, c*16+16); lane l -> row c*16 + l/4, k-octet l%4.
  const int lr = lane >> 2;        // 0..15
  const int lk = (lane & 3) * 8;   // 0,8,16,24
  const u16* Ag0 = A + (size_t)(m0 + wave * 32 + lr) * 768 + lk;
  const u16* Ag1 = Ag0 + 16 * 768;
  const u16* Bg0 = Bt + (size_t)(n0 + wave * 16 + lr) * 768 + lk;
  u16* As0p = As + wave * 1024;  // chunk 2*wave   (byte off = chunk*1024)
  u16* As1p = As0p + 512;        // chunk 2*wave+1
  u16* Bs0p = Bs + wave * 512;   // chunk wave

  f32x4 zero = {0.f, 0.f, 0.f, 0.f};
  f32x4 acc[4][2];
#pragma unroll
  for (int i = 0; i < 4; i++)
#pragma unroll
    for (int j = 0; j < 2; j++) acc[i][j] = zero;

  const int wm = (wave >> 1) * 64;  // wave m-offset: 0 or 64
  const int wn = (wave & 1) * 32;   // wave n-offset: 0 or 32
  const int fm = lane & 15;
  const int fk = (lane >> 4) * 8;

  for (int k0 = 0; k0 < 768; k0 += 32) {
    __syncthreads();  // previous iter's LDS reads done
    GLDS16(Ag0 + k0, As0p);
    GLDS16(Ag1 + k0, As1p);
    GLDS16(Bg0 + k0, Bs0p);
    __syncthreads();  // staging complete (vmcnt drained by barrier)

    bf16x8 af[4], bfrag[2];
#pragma unroll
    for (int i = 0; i < 4; i++)
      af[i] = *(const bf16x8*)&As[(wm + i * 16 + fm) * 32 + fk];
#pragma unroll
    for (int j = 0; j < 2; j++)
      bfrag[j] = *(const bf16x8*)&Bs[(wn + j * 16 + fm) * 32 + fk];
#pragma unroll
    for (int i = 0; i < 4; i++)
#pragma unroll
      for (int j = 0; j < 2; j++)
        acc[i][j] = __builtin_amdgcn_mfma_f32_16x16x32_bf16(af[i], bfrag[j],
                                                            acc[i][j], 0, 0, 0);
  }

  // C/D layout: col = lane&15, row = (lane>>4)*4 + reg  [verified m89/m91]
  const int cq = (lane >> 4) * 4;
#pragma unroll
  for (int i = 0; i < 4; i++) {
    int rbase = m0 + wm + i * 16 + cq;
#pragma unroll
    for (int j = 0; j < 2; j++) {
      int col = n0 + wn + j * 16 + fm;
#pragma unroll
      for (int r = 0; r < 4; r++)
        Y[(size_t)(rbase + r) * 1024 + col] = acc[i][j][r];
    }
  }
}

// ---------------------------------------------------------------------------
// Kernel 4: pooled = (Y + cnt*b)/max(cnt,1); LayerNorm over 1024; write out
// ---------------------------------------------------------------------------
__global__ __launch_bounds__(256) void ln_kernel(const float* __restrict__ Y,
                                                 const int* __restrict__ np,
                                                 const float* __restrict__ b,
                                                 const float* __restrict__ gamma,
                                                 const float* __restrict__ beta,
                                                 float* __restrict__ out) {
  const int row = blockIdx.x;  // 4096
  const int t = threadIdx.x;   // 256, 4 floats each
  const int c = np[row];
  const float inv = c > 0 ? 1.0f / (float)c : 0.0f;
  const float bs = c > 0 ? 1.0f : 0.0f;

  float4 y = ((const float4*)(Y + (size_t)row * 1024))[t];
  float4 bb = ((const float4*)b)[t];
  float4 p;
  p.x = y.x * inv + bb.x * bs;
  p.y = y.y * inv + bb.y * bs;
  p.z = y.z * inv + bb.z * bs;
  p.w = y.w * inv + bb.w * bs;

  float s = p.x + p.y + p.z + p.w;
  float s2 = p.x * p.x + p.y * p.y + p.z * p.z + p.w * p.w;
#pragma unroll
  for (int off = 32; off > 0; off >>= 1) {
    s += __shfl_down(s, off);
    s2 += __shfl_down(s2, off);
  }
  __shared__ float red_s[4], red_s2[4];
  const int wave = t >> 6, lane = t & 63;
  if (lane == 0) { red_s[wave] = s; red_s2[wave] = s2; }
  __syncthreads();
  float ts = red_s[0] + red_s[1] + red_s[2] + red_s[3];
  float ts2 = red_s2[0] + red_s2[1] + red_s2[2] + red_s2[3];
  const float mu = ts * (1.0f / 1024.0f);
  float var = ts2 * (1.0f / 1024.0f) - mu * mu;
  const float rstd = rsqrtf(var + 1e-5f);

  float4 g = ((const float4*)gamma)[t];
  float4 be = ((const float4*)beta)[t];
  float4 o;
  o.x = (p.x - mu) * rstd * g.x + be.x;
  o.y = (p.y - mu) * rstd * g.y + be.y;
  o.z = (p.z - mu) * rstd * g.z + be.z;
  o.w = (p.w - mu) * rstd * g.w + be.w;
  ((float4*)(out + (size_t)row * 1024))[t] = o;
}

// ---------------------------------------------------------------------------
extern "C" void kernel_launch(void* const* d_in, const int* in_sizes, int n_in,
                              void* d_out, int out_size, void* d_ws,
                              size_t ws_size, hipStream_t stream) {
  const float* pv = (const float*)d_in[0];     // [8,512,8,768]
  const int* np = (const int*)d_in[1];         // [8,512]
  const float* W = (const float*)d_in[2];      // [768,1024]
  const float* b = (const float*)d_in[3];      // [1024]
  const float* gamma = (const float*)d_in[4];  // [1024]
  const float* beta = (const float*)d_in[5];   // [1024]
  float* out = (float*)d_out;                  // [8,512,1024]

  char* ws = (char*)d_ws;
  u16* Wt = (u16*)ws;                          // 1,572,864 B
  u16* X = (u16*)(ws + 1572864);               // 6,291,456 B
  float* Y = (float*)(ws + 1572864 + 6291456); // 16,777,216 B

  wcast_kernel<<<dim3(32, 24), 256, 0, stream>>>(W, Wt);
  reduce_kernel<<<4096, 192, 0, stream>>>(pv, np, X);
  gemm_kernel<<<dim3(16, 32), 256, 0, stream>>>(X, Wt, Y);
  ln_kernel<<<4096, 256, 0, stream>>>(Y, np, b, gamma, beta, out);
}

// Round 2
// 178.721 us; speedup vs baseline: 1.0005x; 1.0005x over previous
//
#include <hip/hip_runtime.h>
#include <hip/hip_bf16.h>

typedef unsigned short u16;
typedef __bf16 bf16x8 __attribute__((ext_vector_type(8)));
typedef float f32x4 __attribute__((ext_vector_type(4)));

#define GLDS16(g, l)                                                           \
  __builtin_amdgcn_global_load_lds(                                            \
      (const __attribute__((address_space(1))) unsigned int*)(g),              \
      (__attribute__((address_space(3))) unsigned int*)(l), 16, 0, 0)

static __device__ __forceinline__ u16 f2bf(float f) {
  unsigned int u = __builtin_bit_cast(unsigned int, f);
  u = (u + 0x7fffu + ((u >> 16) & 1u)) >> 16;
  return (u16)u;
}
static __device__ __forceinline__ float bf2f(u16 h) {
  return __builtin_bit_cast(float, (unsigned int)h << 16);
}

// ---------------------------------------------------------------------------
// Kernel 1: W [768][1024] fp32 -> Wt [1024][768] bf16 (transpose via LDS tile)
// ---------------------------------------------------------------------------
__global__ __launch_bounds__(256) void wcast_kernel(const float* __restrict__ W,
                                                    u16* __restrict__ Wt) {
  __shared__ float tile[32][33];
  const int n0 = blockIdx.x * 32;
  const int k0 = blockIdx.y * 32;
  const int t = threadIdx.x;
#pragma unroll
  for (int i = 0; i < 4; i++) {
    int idx = t + i * 256;
    int r = idx >> 5, c = idx & 31;
    tile[r][c] = W[(size_t)(k0 + r) * 1024 + n0 + c];
  }
  __syncthreads();
#pragma unroll
  for (int i = 0; i < 4; i++) {
    int idx = t + i * 256;
    int r = idx >> 5, c = idx & 31;
    Wt[(size_t)(n0 + r) * 768 + k0 + c] = f2bf(tile[c][r]);
  }
}

// ---------------------------------------------------------------------------
// Kernel 2: masked sum over P -> X bf16 [4096][768]
// 2-deep software pipeline: next row's load in flight while accumulating.
// ---------------------------------------------------------------------------
__global__ __launch_bounds__(192) void reduce_kernel(const float* __restrict__ pv,
                                                     const int* __restrict__ np,
                                                     u16* __restrict__ X) {
  const int pos = blockIdx.x;  // 4096
  const int t = threadIdx.x;   // 192 threads x float4 = 768
  const int c = np[pos];
  const float4* base = (const float4*)(pv + (size_t)pos * 8 * 768);
  float4 acc = make_float4(0.f, 0.f, 0.f, 0.f);
  if (c > 0) {
    float4 v = base[t];
    for (int p = 1; p < c; p++) {
      float4 nv = base[p * 192 + t];
      acc.x += v.x; acc.y += v.y; acc.z += v.z; acc.w += v.w;
      v = nv;
    }
    acc.x += v.x; acc.y += v.y; acc.z += v.z; acc.w += v.w;
  }
  ushort4 o;
  o.x = f2bf(acc.x); o.y = f2bf(acc.y); o.z = f2bf(acc.z); o.w = f2bf(acc.w);
  ((ushort4*)(X + (size_t)pos * 768))[t] = o;
}

// ---------------------------------------------------------------------------
// Kernel 3: Y[4096][1024] bf16 = X[4096][768] @ Wt[1024][768]^T
// BM=BN=64, BK=32; 1024 blocks (4/CU); double-buffered LDS, 1 barrier/iter.
// 4 waves, wave tile 32x32 (2x2 MFMA 16x16x32).
// ---------------------------------------------------------------------------
__global__ __launch_bounds__(256) void gemm_kernel(const u16* __restrict__ A,
                                                   const u16* __restrict__ Bt,
                                                   u16* __restrict__ Y) {
  __shared__ __attribute__((aligned(16))) u16 As[2][64 * 32];
  __shared__ __attribute__((aligned(16))) u16 Bs[2][64 * 32];
  const int tid = threadIdx.x;
  const int wave = tid >> 6;
  const int lane = tid & 63;
  const int m0 = blockIdx.y * 64;
  const int n0 = blockIdx.x * 64;

  // Staging: wave w stages rows [w*16, w*16+16) of each tile.
  // lane l -> row w*16 + l/4, k-octet l%4  (HW: lds dest = base + l*16B)
  const int lr = lane >> 2;
  const int lk = (lane & 3) * 8;
  const u16* Ag = A + (size_t)(m0 + wave * 16 + lr) * 768 + lk;
  const u16* Bg = Bt + (size_t)(n0 + wave * 16 + lr) * 768 + lk;
  const int lds_off = wave * 512;  // u16 elements (= wave*1024 bytes)

  f32x4 zero = {0.f, 0.f, 0.f, 0.f};
  f32x4 acc[2][2];
#pragma unroll
  for (int i = 0; i < 2; i++)
#pragma unroll
    for (int j = 0; j < 2; j++) acc[i][j] = zero;

  const int wm = (wave >> 1) * 32;
  const int wn = (wave & 1) * 32;
  const int fm = lane & 15;
  const int fk = (lane >> 4) * 8;

  // Preload tile 0 into buffer 0
  GLDS16(Ag, &As[0][lds_off]);
  GLDS16(Bg, &Bs[0][lds_off]);

#pragma unroll
  for (int i = 0; i < 24; i++) {
    __syncthreads();  // drains vmcnt: buf[i&1] staged; prev reads of buf[(i+1)&1] done
    if (i + 1 < 24) {
      GLDS16(Ag + (i + 1) * 32, &As[(i + 1) & 1][lds_off]);
      GLDS16(Bg + (i + 1) * 32, &Bs[(i + 1) & 1][lds_off]);
    }
    bf16x8 af[2], bfr[2];
#pragma unroll
    for (int ii = 0; ii < 2; ii++)
      af[ii] = *(const bf16x8*)&As[i & 1][(wm + ii * 16 + fm) * 32 + fk];
#pragma unroll
    for (int j = 0; j < 2; j++)
      bfr[j] = *(const bf16x8*)&Bs[i & 1][(wn + j * 16 + fm) * 32 + fk];
#pragma unroll
    for (int ii = 0; ii < 2; ii++)
#pragma unroll
      for (int j = 0; j < 2; j++)
        acc[ii][j] = __builtin_amdgcn_mfma_f32_16x16x32_bf16(af[ii], bfr[j],
                                                             acc[ii][j], 0, 0, 0);
  }

  // C/D layout: col = lane&15, row = (lane>>4)*4 + reg
  const int cq = (lane >> 4) * 4;
#pragma unroll
  for (int ii = 0; ii < 2; ii++) {
    int rbase = m0 + wm + ii * 16 + cq;
#pragma unroll
    for (int j = 0; j < 2; j++) {
      int col = n0 + wn + j * 16 + fm;
#pragma unroll
      for (int r = 0; r < 4; r++)
        Y[(size_t)(rbase + r) * 1024 + col] = f2bf(acc[ii][j][r]);
    }
  }
}

// ---------------------------------------------------------------------------
// Kernel 4: pooled = (Y + cnt*b)/max(cnt,1); LayerNorm over 1024; write out
// ---------------------------------------------------------------------------
__global__ __launch_bounds__(256) void ln_kernel(const u16* __restrict__ Y,
                                                 const int* __restrict__ np,
                                                 const float* __restrict__ b,
                                                 const float* __restrict__ gamma,
                                                 const float* __restrict__ beta,
                                                 float* __restrict__ out) {
  const int row = blockIdx.x;  // 4096
  const int t = threadIdx.x;   // 256 threads x 4 cols
  const int c = np[row];
  const float inv = c > 0 ? 1.0f / (float)c : 0.0f;
  const float bs = c > 0 ? 1.0f : 0.0f;

  ushort4 yv = ((const ushort4*)(Y + (size_t)row * 1024))[t];
  float4 bb = ((const float4*)b)[t];
  float4 p;
  p.x = bf2f(yv.x) * inv + bb.x * bs;
  p.y = bf2f(yv.y) * inv + bb.y * bs;
  p.z = bf2f(yv.z) * inv + bb.z * bs;
  p.w = bf2f(yv.w) * inv + bb.w * bs;

  float s = p.x + p.y + p.z + p.w;
  float s2 = p.x * p.x + p.y * p.y + p.z * p.z + p.w * p.w;
#pragma unroll
  for (int off = 32; off > 0; off >>= 1) {
    s += __shfl_down(s, off);
    s2 += __shfl_down(s2, off);
  }
  __shared__ float red_s[4], red_s2[4];
  const int wave = t >> 6, lane = t & 63;
  if (lane == 0) { red_s[wave] = s; red_s2[wave] = s2; }
  __syncthreads();
  float ts = red_s[0] + red_s[1] + red_s[2] + red_s[3];
  float ts2 = red_s2[0] + red_s2[1] + red_s2[2] + red_s2[3];
  const float mu = ts * (1.0f / 1024.0f);
  float var = ts2 * (1.0f / 1024.0f) - mu * mu;
  const float rstd = rsqrtf(var + 1e-5f);

  float4 g = ((const float4*)gamma)[t];
  float4 be = ((const float4*)beta)[t];
  float4 o;
  o.x = (p.x - mu) * rstd * g.x + be.x;
  o.y = (p.y - mu) * rstd * g.y + be.y;
  o.z = (p.z - mu) * rstd * g.z + be.z;
  o.w = (p.w - mu) * rstd * g.w + be.w;
  ((float4*)(out + (size_t)row * 1024))[t] = o;
}

// ---------------------------------------------------------------------------
extern "C" void kernel_launch(void* const* d_in, const int* in_sizes, int n_in,
                              void* d_out, int out_size, void* d_ws,
                              size_t ws_size, hipStream_t stream) {
  const float* pv = (const float*)d_in[0];     // [8,512,8,768]
  const int* np = (const int*)d_in[1];         // [8,512]
  const float* W = (const float*)d_in[2];      // [768,1024]
  const float* b = (const float*)d_in[3];      // [1024]
  const float* gamma = (const float*)d_in[4];  // [1024]
  const float* beta = (const float*)d_in[5];   // [1024]
  float* out = (float*)d_out;                  // [8,512,1024]

  char* ws = (char*)d_ws;
  u16* Wt = (u16*)ws;                          // 1,572,864 B
  u16* X = (u16*)(ws + 1572864);               // 6,291,456 B
  u16* Y = (u16*)(ws + 1572864 + 6291456);     // 8,388,608 B

  wcast_kernel<<<dim3(32, 24), 256, 0, stream>>>(W, Wt);
  reduce_kernel<<<4096, 192, 0, stream>>>(pv, np, X);
  gemm_kernel<<<dim3(16, 64), 256, 0, stream>>>(X, Wt, Y);
  ln_kernel<<<4096, 256, 0, stream>>>(Y, np, b, gamma, beta, out);
}

// Round 3
// 176.101 us; speedup vs baseline: 1.0153x; 1.0149x over previous
//
#include <hip/hip_runtime.h>
#include <hip/hip_bf16.h>

typedef unsigned short u16;
typedef __bf16 bf16x8 __attribute__((ext_vector_type(8)));
typedef float f32x4 __attribute__((ext_vector_type(4)));

#define GLDS16(g, l)                                                           \
  __builtin_amdgcn_global_load_lds(                                            \
      (const __attribute__((address_space(1))) unsigned int*)(g),              \
      (__attribute__((address_space(3))) unsigned int*)(l), 16, 0, 0)

static __device__ __forceinline__ u16 f2bf(float f) {
  unsigned int u = __builtin_bit_cast(unsigned int, f);
  u = (u + 0x7fffu + ((u >> 16) & 1u)) >> 16;
  return (u16)u;
}
static __device__ __forceinline__ float bf2f(u16 h) {
  return __builtin_bit_cast(float, (unsigned int)h << 16);
}

// ---------------------------------------------------------------------------
// Kernel 1 (merged): blocks [0,768): W fp32 -> Wt bf16 transpose
//                    blocks [768,4864): masked P-sum -> X bf16 [4096][768]
// ---------------------------------------------------------------------------
__global__ __launch_bounds__(256) void prep_kernel(const float* __restrict__ W,
                                                   u16* __restrict__ Wt,
                                                   const float* __restrict__ pv,
                                                   const int* __restrict__ np,
                                                   u16* __restrict__ X) {
  __shared__ float tile[32][33];
  const int bid = blockIdx.x;
  const int t = threadIdx.x;
  if (bid < 768) {  // --- wcast: 32x32 transpose tile ---
    const int n0 = (bid & 31) * 32;
    const int k0 = (bid >> 5) * 32;
#pragma unroll
    for (int i = 0; i < 4; i++) {
      int idx = t + i * 256;
      int r = idx >> 5, c = idx & 31;
      tile[r][c] = W[(size_t)(k0 + r) * 1024 + n0 + c];
    }
    __syncthreads();
#pragma unroll
    for (int i = 0; i < 4; i++) {
      int idx = t + i * 256;
      int r = idx >> 5, c = idx & 31;
      Wt[(size_t)(n0 + r) * 768 + k0 + c] = f2bf(tile[c][r]);
    }
  } else {  // --- reduce: one position per block, threads 0..191 ---
    if (t >= 192) return;
    const int pos = bid - 768;
    const int c = np[pos];
    const float4* base = (const float4*)(pv + (size_t)pos * 8 * 768);
    float4 acc = make_float4(0.f, 0.f, 0.f, 0.f);
    if (c > 0) {
      float4 v = base[t];
      for (int p = 1; p < c; p++) {
        float4 nv = base[p * 192 + t];
        acc.x += v.x; acc.y += v.y; acc.z += v.z; acc.w += v.w;
        v = nv;
      }
      acc.x += v.x; acc.y += v.y; acc.z += v.z; acc.w += v.w;
    }
    ushort4 o;
    o.x = f2bf(acc.x); o.y = f2bf(acc.y); o.z = f2bf(acc.z); o.w = f2bf(acc.w);
    ((ushort4*)(X + (size_t)pos * 768))[t] = o;
  }
}

// ---------------------------------------------------------------------------
// Kernel 2: Y[4096][1024] bf16 = X[4096][768] @ Wt[1024][768]^T
// BM=BN=64, BK=32; 1024 blocks (4/CU); double-buffered LDS, 1 barrier/iter.
// (unchanged from R2 — conflict-free BK=32 layout, latency hidden)
// ---------------------------------------------------------------------------
__global__ __launch_bounds__(256) void gemm_kernel(const u16* __restrict__ A,
                                                   const u16* __restrict__ Bt,
                                                   u16* __restrict__ Y) {
  __shared__ __attribute__((aligned(16))) u16 As[2][64 * 32];
  __shared__ __attribute__((aligned(16))) u16 Bs[2][64 * 32];
  const int tid = threadIdx.x;
  const int wave = tid >> 6;
  const int lane = tid & 63;
  const int m0 = blockIdx.y * 64;
  const int n0 = blockIdx.x * 64;

  const int lr = lane >> 2;
  const int lk = (lane & 3) * 8;
  const u16* Ag = A + (size_t)(m0 + wave * 16 + lr) * 768 + lk;
  const u16* Bg = Bt + (size_t)(n0 + wave * 16 + lr) * 768 + lk;
  const int lds_off = wave * 512;

  f32x4 zero = {0.f, 0.f, 0.f, 0.f};
  f32x4 acc[2][2];
#pragma unroll
  for (int i = 0; i < 2; i++)
#pragma unroll
    for (int j = 0; j < 2; j++) acc[i][j] = zero;

  const int wm = (wave >> 1) * 32;
  const int wn = (wave & 1) * 32;
  const int fm = lane & 15;
  const int fk = (lane >> 4) * 8;

  GLDS16(Ag, &As[0][lds_off]);
  GLDS16(Bg, &Bs[0][lds_off]);

#pragma unroll
  for (int i = 0; i < 24; i++) {
    __syncthreads();
    if (i + 1 < 24) {
      GLDS16(Ag + (i + 1) * 32, &As[(i + 1) & 1][lds_off]);
      GLDS16(Bg + (i + 1) * 32, &Bs[(i + 1) & 1][lds_off]);
    }
    bf16x8 af[2], bfr[2];
#pragma unroll
    for (int ii = 0; ii < 2; ii++)
      af[ii] = *(const bf16x8*)&As[i & 1][(wm + ii * 16 + fm) * 32 + fk];
#pragma unroll
    for (int j = 0; j < 2; j++)
      bfr[j] = *(const bf16x8*)&Bs[i & 1][(wn + j * 16 + fm) * 32 + fk];
#pragma unroll
    for (int ii = 0; ii < 2; ii++)
#pragma unroll
      for (int j = 0; j < 2; j++)
        acc[ii][j] = __builtin_amdgcn_mfma_f32_16x16x32_bf16(af[ii], bfr[j],
                                                             acc[ii][j], 0, 0, 0);
  }

  const int cq = (lane >> 4) * 4;
#pragma unroll
  for (int ii = 0; ii < 2; ii++) {
    int rbase = m0 + wm + ii * 16 + cq;
#pragma unroll
    for (int j = 0; j < 2; j++) {
      int col = n0 + wn + j * 16 + fm;
#pragma unroll
      for (int r = 0; r < 4; r++)
        Y[(size_t)(rbase + r) * 1024 + col] = f2bf(acc[ii][j][r]);
    }
  }
}

// ---------------------------------------------------------------------------
// Kernel 3: wave-per-row LN. 4 rows/block (one per wave), grid 1024.
// pooled = (Y + cnt*b)/max(cnt,1); LayerNorm over 1024; no LDS, no barrier.
// ---------------------------------------------------------------------------
__global__ __launch_bounds__(256) void ln_kernel(const u16* __restrict__ Y,
                                                 const int* __restrict__ np,
                                                 const float* __restrict__ b,
                                                 const float* __restrict__ gamma,
                                                 const float* __restrict__ beta,
                                                 float* __restrict__ out) {
  const int t = threadIdx.x;
  const int wave = t >> 6, lane = t & 63;
  const int row = blockIdx.x * 4 + wave;
  const int c = np[row];
  const float inv = c > 0 ? 1.0f / (float)c : 0.0f;
  const float bs = c > 0 ? 1.0f : 0.0f;

  const ushort4* yrow = (const ushort4*)(Y + (size_t)row * 1024);
  float4 p[4];
  float s = 0.f, s2 = 0.f;
#pragma unroll
  for (int i = 0; i < 4; i++) {
    ushort4 yv = yrow[i * 64 + lane];
    float4 bb = ((const float4*)b)[i * 64 + lane];
    p[i].x = bf2f(yv.x) * inv + bb.x * bs;
    p[i].y = bf2f(yv.y) * inv + bb.y * bs;
    p[i].z = bf2f(yv.z) * inv + bb.z * bs;
    p[i].w = bf2f(yv.w) * inv + bb.w * bs;
    s += p[i].x + p[i].y + p[i].z + p[i].w;
    s2 += p[i].x * p[i].x + p[i].y * p[i].y + p[i].z * p[i].z + p[i].w * p[i].w;
  }
#pragma unroll
  for (int off = 32; off > 0; off >>= 1) {
    s += __shfl_down(s, off);
    s2 += __shfl_down(s2, off);
  }
  s = __shfl(s, 0);
  s2 = __shfl(s2, 0);
  const float mu = s * (1.0f / 1024.0f);
  float var = s2 * (1.0f / 1024.0f) - mu * mu;
  const float rstd = rsqrtf(var + 1e-5f);

  float4* orow = (float4*)(out + (size_t)row * 1024);
#pragma unroll
  for (int i = 0; i < 4; i++) {
    float4 g = ((const float4*)gamma)[i * 64 + lane];
    float4 be = ((const float4*)beta)[i * 64 + lane];
    float4 o;
    o.x = (p[i].x - mu) * rstd * g.x + be.x;
    o.y = (p[i].y - mu) * rstd * g.y + be.y;
    o.z = (p[i].z - mu) * rstd * g.z + be.z;
    o.w = (p[i].w - mu) * rstd * g.w + be.w;
    orow[i * 64 + lane] = o;
  }
}

// ---------------------------------------------------------------------------
extern "C" void kernel_launch(void* const* d_in, const int* in_sizes, int n_in,
                              void* d_out, int out_size, void* d_ws,
                              size_t ws_size, hipStream_t stream) {
  const float* pv = (const float*)d_in[0];     // [8,512,8,768]
  const int* np = (const int*)d_in[1];         // [8,512]
  const float* W = (const float*)d_in[2];      // [768,1024]
  const float* b = (const float*)d_in[3];      // [1024]
  const float* gamma = (const float*)d_in[4];  // [1024]
  const float* beta = (const float*)d_in[5];   // [1024]
  float* out = (float*)d_out;                  // [8,512,1024]

  char* ws = (char*)d_ws;
  u16* Wt = (u16*)ws;                          // 1,572,864 B
  u16* X = (u16*)(ws + 1572864);               // 6,291,456 B
  u16* Y = (u16*)(ws + 1572864 + 6291456);     // 8,388,608 B

  prep_kernel<<<4864, 256, 0, stream>>>(W, Wt, pv, np, X);
  gemm_kernel<<<dim3(16, 64), 256, 0, stream>>>(X, Wt, Y);
  ln_kernel<<<1024, 256, 0, stream>>>(Y, np, b, gamma, beta, out);
}